// Round 8
// baseline (93.345 us; speedup 1.0000x reference)
//
#include <hip/hip_runtime.h>
#include <stdint.h>

#define N2  361
#define TPB 256
#define EPT 8

// d_ws layout: byte 0: uint32 counter; bytes 64..: int2 records.
// Record: x = s (segment start), y = r | lencode<<22 | p<<26
//   lencode = min(len,7) if len<=7 else 15 (15 => passB re-reads indptr).
//   r < 2^22 (B*N2 = 2,957,312 fits).

__device__ __forceinline__ uint32_t mbcnt64(uint64_t m) {
    return __builtin_amdgcn_mbcnt_hi((uint32_t)(m >> 32),
           __builtin_amdgcn_mbcnt_lo((uint32_t)m, 0u));
}

__global__ void zero_counter(uint32_t* c) { *c = 0u; }

// ---------------- Pass A: streaming base hash + worklist compaction --------
__global__ __launch_bounds__(TPB)
void passA(const void* __restrict__ legal_p,     // (B,N2) bool/int32/f32
           const int*  __restrict__ cur_player,  // (B,)
           const int*  __restrict__ cur_hash,    // (B,)
           const int*  __restrict__ Z,           // (3,N2)
           const void* __restrict__ cap_p,       // (B,N2)
           const int*  __restrict__ indptr,      // (B*N2+1,)
           int*        __restrict__ out,
           uint32_t*   __restrict__ counter,
           int2*       __restrict__ recs,
           int maxrec, int total, int Bm1)
{
    __shared__ int T[2 * N2];   // [i]=Z0^Z1, [i+N2]=Z0^Z2
    const int tid = threadIdx.x;

    for (int t = tid; t < N2; t += TPB) {
        int z0 = Z[t], z1 = Z[N2 + t], z2 = Z[2 * N2 + t];
        T[t] = z0 ^ z1; T[t + N2] = z0 ^ z2;
    }

    // Mask element-width detection (wave-uniform): int32 masks -> words in
    // {0,1}; float32 -> {0,0x3f800000}; packed-byte bool masks essentially
    // never match all 16 words (P ~ 8^-16).
    const uint32_t* wdet = (const uint32_t*)legal_p;
    bool layout4 = true;
    #pragma unroll
    for (int k = 0; k < 16; ++k) {
        uint32_t v = wdet[k];
        layout4 = layout4 && (v == 0u || v == 1u || v == 0x3f800000u);
    }

    __syncthreads();

    const int  r0   = (blockIdx.x * TPB + tid) * EPT;
    const int  lane = tid & 63;
    const bool block_full = (((int)blockIdx.x + 1) * TPB * EPT) <= total;

    if (block_full) {
        const int4 ia = *(const int4*)(indptr + r0);
        const int4 ib = *(const int4*)(indptr + r0 + 4);
        const int  ic = indptr[r0 + 8];
        const int s0=ia.x, s1=ia.y, s2=ia.z, s3=ia.w;
        const int s4=ib.x, s5=ib.y, s6=ib.z, s7=ib.w, s8=ic;

        uint32_t lB0,lB1,lB2,lB3,lB4,lB5,lB6,lB7;
        uint32_t cB0,cB1,cB2,cB3,cB4,cB5,cB6,cB7;
        if (layout4) {
            uint4 la = *(const uint4*)((const uint32_t*)legal_p + r0);
            uint4 lb = *(const uint4*)((const uint32_t*)legal_p + r0 + 4);
            uint4 ca = *(const uint4*)((const uint32_t*)cap_p   + r0);
            uint4 cb = *(const uint4*)((const uint32_t*)cap_p   + r0 + 4);
            lB0=la.x; lB1=la.y; lB2=la.z; lB3=la.w;
            lB4=lb.x; lB5=lb.y; lB6=lb.z; lB7=lb.w;
            cB0=ca.x; cB1=ca.y; cB2=ca.z; cB3=ca.w;
            cB4=cb.x; cB5=cb.y; cB6=cb.z; cB7=cb.w;
        } else {
            uint2 lu = *(const uint2*)((const uint8_t*)legal_p + r0);
            uint2 cu = *(const uint2*)((const uint8_t*)cap_p   + r0);
            lB0=lu.x&255u; lB1=(lu.x>>8)&255u; lB2=(lu.x>>16)&255u; lB3=lu.x>>24;
            lB4=lu.y&255u; lB5=(lu.y>>8)&255u; lB6=(lu.y>>16)&255u; lB7=lu.y>>24;
            cB0=cu.x&255u; cB1=(cu.x>>8)&255u; cB2=(cu.x>>16)&255u; cB3=cu.x>>24;
            cB4=cu.y&255u; cB5=(cu.y>>8)&255u; cB6=(cu.y>>16)&255u; cB7=cu.y>>24;
        }

        const unsigned bA = (unsigned)r0 / 361u;
        const int      i0 = r0 - (int)bA * 361;
        unsigned bBi = bA + 1; if (bBi > (unsigned)Bm1) bBi = (unsigned)Bm1;
        const int pA_ = cur_player[bA],  hA_ = cur_hash[bA];
        const int pB_ = cur_player[bBi], hB_ = cur_hash[bBi];

#define ELEM(e, SLO, SHI, LB, CB)                                        \
        const int  len##e  = (SHI) - (SLO);                              \
        const bool keep##e = ((LB)!=0u) & ((CB)!=0u) & (len##e > 0);     \
        const int  io##e   = i0 + (e);                                   \
        const bool wr##e   = io##e >= N2;                                \
        const int  ik##e   = wr##e ? io##e - N2 : io##e;                 \
        const int  pl##e   = wr##e ? pB_ : pA_;                          \
        const int  res##e  = (wr##e ? hB_ : hA_) ^ T[ik##e + (pl##e ? N2 : 0)];

        ELEM(0, s0, s1, lB0, cB0)
        ELEM(1, s1, s2, lB1, cB1)
        ELEM(2, s2, s3, lB2, cB2)
        ELEM(3, s3, s4, lB3, cB3)
        ELEM(4, s4, s5, lB4, cB4)
        ELEM(5, s5, s6, lB5, cB5)
        ELEM(6, s6, s7, lB6, cB6)
        ELEM(7, s7, s8, lB7, cB7)
#undef ELEM

        *(int4*)(out + r0)     = make_int4(res0, res1, res2, res3);
        *(int4*)(out + r0 + 4) = make_int4(res4, res5, res6, res7);

        // ---- wave-aggregated worklist compaction ----
        const uint64_t m0=__ballot(keep0), m1=__ballot(keep1),
                       m2=__ballot(keep2), m3=__ballot(keep3),
                       m4=__ballot(keep4), m5=__ballot(keep5),
                       m6=__ballot(keep6), m7=__ballot(keep7);
        const uint32_t c0=__popcll(m0), c1=__popcll(m1), c2=__popcll(m2),
                       c3=__popcll(m3), c4=__popcll(m4), c5=__popcll(m5),
                       c6=__popcll(m6), c7=__popcll(m7);
        const uint32_t wtotal = c0+c1+c2+c3+c4+c5+c6+c7;

        uint32_t base = 0;
        if (lane == 0) base = atomicAdd(counter, wtotal);
        base = (uint32_t)__shfl((int)base, 0, 64);

        uint32_t cum = base;
#define EMIT(e, SLO)                                                     \
        if (keep##e) {                                                   \
            uint32_t slot = cum + mbcnt64(m##e);                         \
            int lc = len##e <= 7 ? len##e : 15;                          \
            if (slot < (uint32_t)maxrec)                                 \
                recs[slot] = make_int2((SLO),                            \
                    (r0 + (e)) | (lc << 22) | (pl##e << 26));            \
        }                                                                \
        cum += c##e;

        EMIT(0, s0) EMIT(1, s1) EMIT(2, s2) EMIT(3, s3)
        EMIT(4, s4) EMIT(5, s5) EMIT(6, s6) EMIT(7, s7)
#undef EMIT
    } else {
        // generic tail (unused for bench shape: total % 2048 == 0)
        for (int e = 0; e < EPT; ++e) {
            const int r = r0 + e;
            if (r >= total) break;
            const int s = indptr[r], en = indptr[r + 1], len = en - s;
            bool lg, cp;
            if (layout4) {
                lg = ((const int*)legal_p)[r] != 0;
                cp = ((const int*)cap_p)[r]   != 0;
            } else {
                lg = ((const uint8_t*)legal_p)[r] != 0;
                cp = ((const uint8_t*)cap_p)[r]   != 0;
            }
            const unsigned bb = (unsigned)r / 361u;
            const int ii = r - (int)bb * 361;
            const int pp = cur_player[bb];
            out[r] = cur_hash[bb] ^ T[ii + (pp ? N2 : 0)];
            if (lg && cp && len > 0) {
                uint32_t slot = atomicAdd(counter, 1u);
                int lc = len <= 7 ? len : 15;
                if (slot < (uint32_t)maxrec)
                    recs[slot] = make_int2(s, r | (lc << 22) | (pp << 26));
            }
        }
    }
}

// ---------------- Pass B: dense gather over the worklist -------------------
__global__ __launch_bounds__(TPB)
void passB(const int* __restrict__ Z,
           const int* __restrict__ cap_idx,
           const int* __restrict__ cur_hash,
           const int* __restrict__ indptr,
           const uint32_t* __restrict__ counter,
           const int2* __restrict__ recs,
           int*       __restrict__ out,
           int maxrec, int Lm1)
{
    __shared__ int T[2 * N2];
    for (int t = threadIdx.x; t < N2; t += TPB) {
        int z0 = Z[t], z1 = Z[N2 + t], z2 = Z[2 * N2 + t];
        T[t] = z0 ^ z1; T[t + N2] = z0 ^ z2;
    }
    __syncthreads();

    uint32_t n = *counter;
    if (n > (uint32_t)maxrec) n = (uint32_t)maxrec;

    for (uint32_t k = blockIdx.x * TPB + threadIdx.x; k < n;
         k += gridDim.x * TPB) {
        const int2 rec = recs[k];
        const int s  = rec.x;
        const int y  = rec.y;
        const int r  = y & 0x3FFFFF;
        const int lc = (y >> 22) & 15;
        const int p  = (y >> 26) & 1;
        const int cO = p ? 0 : N2;

        int acc;
        if (lc < 15) {
            // lc = true len in [1,7]: 7 independent clamped loads.
            const int j1=s+1, j2=s+2, j3=s+3, j4=s+4, j5=s+5, j6=s+6;
            const int g0 = cap_idx[s];
            const int g1 = cap_idx[j1 > Lm1 ? Lm1 : j1];
            const int g2 = cap_idx[j2 > Lm1 ? Lm1 : j2];
            const int g3 = cap_idx[j3 > Lm1 ? Lm1 : j3];
            const int g4 = cap_idx[j4 > Lm1 ? Lm1 : j4];
            const int g5 = cap_idx[j5 > Lm1 ? Lm1 : j5];
            const int g6 = cap_idx[j6 > Lm1 ? Lm1 : j6];
            acc  = T[g0 + cO];
            acc ^= (1 < lc) ? T[g1 + cO] : 0;
            acc ^= (2 < lc) ? T[g2 + cO] : 0;
            acc ^= (3 < lc) ? T[g3 + cO] : 0;
            acc ^= (4 < lc) ? T[g4 + cO] : 0;
            acc ^= (5 < lc) ? T[g5 + cO] : 0;
            acc ^= (6 < lc) ? T[g6 + cO] : 0;
        } else {
            // len > 7 (not present in bench data): re-derive from indptr.
            const int en = indptr[r + 1];
            acc = 0;
            for (int j = s; j < en; ++j) acc ^= T[cap_idx[j] + cO];
        }

        const unsigned b = (unsigned)r / 361u;
        const int ik = r - (int)b * 361;
        out[r] = cur_hash[b] ^ T[ik + (p ? N2 : 0)] ^ acc;
    }
}

extern "C" void kernel_launch(void* const* d_in, const int* in_sizes, int n_in,
                              void* d_out, int out_size, void* d_ws, size_t ws_size,
                              hipStream_t stream) {
    // 0: legal_mask (B,N2)  1: current_player (B,)  2: current_hash (B,)
    // 3: ZposT (3,N2)       4: can_capture_any (B,N2)
    // 5: cap_indptr (B*N2+1,)  6: cap_indices (L,)
    const void* legal  = d_in[0];
    const int*  player = (const int*)d_in[1];
    const int*  hash   = (const int*)d_in[2];
    const int*  Z      = (const int*)d_in[3];
    const void* cap    = d_in[4];
    const int*  indptr = (const int*)d_in[5];
    const int*  capidx = (const int*)d_in[6];
    int*        out    = (int*)d_out;

    uint32_t* counter = (uint32_t*)d_ws;
    int2*     recs    = (int2*)((char*)d_ws + 64);
    const int maxrec  = (int)((ws_size - 64) / sizeof(int2));

    const int total = out_size;            // B*N2 = 2,957,312
    const int Lm1   = in_sizes[6] - 1;
    const int Bm1   = in_sizes[1] - 1;

    const int blocksA = (total + TPB * EPT - 1) / (TPB * EPT);   // 1444

    zero_counter<<<1, 1, 0, stream>>>(counter);
    passA<<<blocksA, TPB, 0, stream>>>(legal, player, hash, Z, cap, indptr,
                                       out, counter, recs, maxrec, total, Bm1);
    passB<<<2048, TPB, 0, stream>>>(Z, capidx, hash, indptr, counter, recs,
                                    out, maxrec, Lm1);
}

// Round 9
// 22.435 us; speedup vs baseline: 4.1608x; 4.1608x over previous
//
#include <hip/hip_runtime.h>
#include <stdint.h>

#define N2   361
#define TPB  256
#define EPT  8
#define QCAP (TPB * EPT)   // 2048: worst case every element kept

// Fused single-kernel, two-phase-per-block design:
//   phase 1 (streaming): EPT=8 burst of indptr+masks, base hash
//     out[r] = hash ^ place written for ALL r (int4 stores), kept elements
//     compacted into an LDS queue via ballots (deterministic, no atomics).
//   phase 2 (dense gather): all 64 lanes active; each queue entry does 7
//     clamped cap_idx loads + swizzled-LDS T lookups, overwrites out[r].
// T is index-swizzled (i + (i>>5)) so phase-1 place lookups (lane stride 8,
// otherwise a 16-way bank conflict) spread across all banks.

__device__ __forceinline__ uint32_t mbcnt64(uint64_t m) {
    return __builtin_amdgcn_mbcnt_hi((uint32_t)(m >> 32),
           __builtin_amdgcn_mbcnt_lo((uint32_t)m, 0u));
}

__device__ __forceinline__ int swz(int i) { return i + (i >> 5); }

__global__ __launch_bounds__(TPB, 4)
void superko_fused(const void* __restrict__ legal_p,     // (B,N2) bool/int32/f32
                   const int*  __restrict__ cur_player,  // (B,)
                   const int*  __restrict__ cur_hash,    // (B,)
                   const int*  __restrict__ Z,           // (3,N2)
                   const void* __restrict__ cap_p,       // (B,N2)
                   const int*  __restrict__ indptr,      // (B*N2+1,)
                   const int*  __restrict__ cap_idx,     // (L,)
                   int*        __restrict__ out,         // (B,N2)
                   int total, int Lm1, int Bm1)
{
    __shared__ int T[2 * N2 + ((2 * N2) >> 5) + 1];   // 745 swizzled slots
    __shared__ int qS[QCAP];     // segment start
    __shared__ int qB[QCAP];     // base hash (h ^ place)
    __shared__ int qR[QCAP];     // r | lc<<22 | p<<26
    __shared__ int wtot[4];

    const int tid  = threadIdx.x;
    const int wv   = tid >> 6;
    const int lane = tid & 63;

    for (int t = tid; t < N2; t += TPB) {
        int z0 = Z[t], z1 = Z[N2 + t], z2 = Z[2 * N2 + t];
        T[swz(t)]      = z0 ^ z1;
        T[swz(t + N2)] = z0 ^ z2;
    }

    // Mask element-width detection (wave-uniform): int32 masks -> words in
    // {0,1}; float32 -> {0,0x3f800000}; packed-byte bool masks essentially
    // never match all 16 words (P ~ 8^-16).
    const uint32_t* wdet = (const uint32_t*)legal_p;
    bool layout4 = true;
    #pragma unroll
    for (int k = 0; k < 16; ++k) {
        uint32_t v = wdet[k];
        layout4 = layout4 && (v == 0u || v == 1u || v == 0x3f800000u);
    }

    const int  r0 = (blockIdx.x * TPB + tid) * EPT;
    const bool block_full = (((int)blockIdx.x + 1) * TPB * EPT) <= total;

    if (block_full) {
        // ---- phase 1: deep independent load burst ----
        const int4 ia = *(const int4*)(indptr + r0);
        const int4 ib = *(const int4*)(indptr + r0 + 4);
        const int  ic = indptr[r0 + 8];
        const int s0=ia.x, s1=ia.y, s2=ia.z, s3=ia.w;
        const int s4=ib.x, s5=ib.y, s6=ib.z, s7=ib.w, s8=ic;

        uint32_t lB0,lB1,lB2,lB3,lB4,lB5,lB6,lB7;
        uint32_t cB0,cB1,cB2,cB3,cB4,cB5,cB6,cB7;
        if (layout4) {
            uint4 la = *(const uint4*)((const uint32_t*)legal_p + r0);
            uint4 lb = *(const uint4*)((const uint32_t*)legal_p + r0 + 4);
            uint4 ca = *(const uint4*)((const uint32_t*)cap_p   + r0);
            uint4 cb = *(const uint4*)((const uint32_t*)cap_p   + r0 + 4);
            lB0=la.x; lB1=la.y; lB2=la.z; lB3=la.w;
            lB4=lb.x; lB5=lb.y; lB6=lb.z; lB7=lb.w;
            cB0=ca.x; cB1=ca.y; cB2=ca.z; cB3=ca.w;
            cB4=cb.x; cB5=cb.y; cB6=cb.z; cB7=cb.w;
        } else {
            uint2 lu = *(const uint2*)((const uint8_t*)legal_p + r0);
            uint2 cu = *(const uint2*)((const uint8_t*)cap_p   + r0);
            lB0=lu.x&255u; lB1=(lu.x>>8)&255u; lB2=(lu.x>>16)&255u; lB3=lu.x>>24;
            lB4=lu.y&255u; lB5=(lu.y>>8)&255u; lB6=(lu.y>>16)&255u; lB7=lu.y>>24;
            cB0=cu.x&255u; cB1=(cu.x>>8)&255u; cB2=(cu.x>>16)&255u; cB3=cu.x>>24;
            cB4=cu.y&255u; cB5=(cu.y>>8)&255u; cB6=(cu.y>>16)&255u; cB7=cu.y>>24;
        }

        const unsigned bA = (unsigned)r0 / 361u;
        const int      i0 = r0 - (int)bA * 361;
        unsigned bBi = bA + 1; if (bBi > (unsigned)Bm1) bBi = (unsigned)Bm1;
        const int pA_ = cur_player[bA],  hA_ = cur_hash[bA];
        const int pB_ = cur_player[bBi], hB_ = cur_hash[bBi];

        __syncthreads();   // T ready (burst loads above don't touch LDS)

#define ELEM(e, SLO, SHI, LB, CB)                                          \
        const int  len##e  = (SHI) - (SLO);                                \
        const bool keep##e = ((LB)!=0u) & ((CB)!=0u) & (len##e > 0);       \
        const int  io##e   = i0 + (e);                                     \
        const bool wr##e   = io##e >= N2;                                  \
        const int  ik##e   = wr##e ? io##e - N2 : io##e;                   \
        const int  pl##e   = wr##e ? pB_ : pA_;                            \
        const int  res##e  = (wr##e ? hB_ : hA_) ^                         \
                             T[swz(ik##e + (pl##e ? N2 : 0))];

        ELEM(0, s0, s1, lB0, cB0)
        ELEM(1, s1, s2, lB1, cB1)
        ELEM(2, s2, s3, lB2, cB2)
        ELEM(3, s3, s4, lB3, cB3)
        ELEM(4, s4, s5, lB4, cB4)
        ELEM(5, s5, s6, lB5, cB5)
        ELEM(6, s6, s7, lB6, cB6)
        ELEM(7, s7, s8, lB7, cB7)
#undef ELEM

        *(int4*)(out + r0)     = make_int4(res0, res1, res2, res3);
        *(int4*)(out + r0 + 4) = make_int4(res4, res5, res6, res7);

        // ---- deterministic in-block compaction (no atomics) ----
        const uint64_t m0=__ballot(keep0), m1=__ballot(keep1),
                       m2=__ballot(keep2), m3=__ballot(keep3),
                       m4=__ballot(keep4), m5=__ballot(keep5),
                       m6=__ballot(keep6), m7=__ballot(keep7);
        const uint32_t c0=__popcll(m0), c1=__popcll(m1), c2=__popcll(m2),
                       c3=__popcll(m3), c4=__popcll(m4), c5=__popcll(m5),
                       c6=__popcll(m6), c7=__popcll(m7);
        const uint32_t wtotal = c0+c1+c2+c3+c4+c5+c6+c7;

        if (lane == 0) wtot[wv] = (int)wtotal;
        __syncthreads();
        const int w0 = wtot[0], w1 = wtot[1], w2 = wtot[2], w3 = wtot[3];
        const int count = w0 + w1 + w2 + w3;
        uint32_t cum = (wv > 0 ? w0 : 0) + (wv > 1 ? w1 : 0) + (wv > 2 ? w2 : 0);

#define EMIT(e, SLO)                                                       \
        if (keep##e) {                                                     \
            const uint32_t slot = cum + mbcnt64(m##e);                     \
            const int lc = len##e <= 7 ? len##e : 15;                      \
            qS[slot] = (SLO);                                              \
            qB[slot] = res##e;                                             \
            qR[slot] = (r0 + (e)) | (lc << 22) | (pl##e << 26);            \
        }                                                                  \
        cum += c##e;

        EMIT(0, s0) EMIT(1, s1) EMIT(2, s2) EMIT(3, s3)
        EMIT(4, s4) EMIT(5, s5) EMIT(6, s6) EMIT(7, s7)
#undef EMIT

        __syncthreads();   // queue ready; phase-1 stores drained by barrier

        // ---- phase 2: dense gather, all lanes active ----
        for (int k = tid; k < count; k += TPB) {
            const int s  = qS[k];
            const int bs = qB[k];
            const int y  = qR[k];
            const int r  = y & 0x3FFFFF;
            const int lc = (y >> 22) & 15;
            const int p  = (y >> 26) & 1;
            const int cO = p ? 0 : N2;

            int acc;
            if (lc < 15) {
                const int j1=s+1, j2=s+2, j3=s+3, j4=s+4, j5=s+5, j6=s+6;
                const int g0 = cap_idx[s];
                const int g1 = cap_idx[j1 > Lm1 ? Lm1 : j1];
                const int g2 = cap_idx[j2 > Lm1 ? Lm1 : j2];
                const int g3 = cap_idx[j3 > Lm1 ? Lm1 : j3];
                const int g4 = cap_idx[j4 > Lm1 ? Lm1 : j4];
                const int g5 = cap_idx[j5 > Lm1 ? Lm1 : j5];
                const int g6 = cap_idx[j6 > Lm1 ? Lm1 : j6];
                acc  = T[swz(g0 + cO)];
                acc ^= (1 < lc) ? T[swz(g1 + cO)] : 0;
                acc ^= (2 < lc) ? T[swz(g2 + cO)] : 0;
                acc ^= (3 < lc) ? T[swz(g3 + cO)] : 0;
                acc ^= (4 < lc) ? T[swz(g4 + cO)] : 0;
                acc ^= (5 < lc) ? T[swz(g5 + cO)] : 0;
                acc ^= (6 < lc) ? T[swz(g6 + cO)] : 0;
            } else {
                // len > 7 (absent in bench data): re-derive end from indptr.
                const int en = indptr[r + 1];
                acc = 0;
                for (int j = s; j < en; ++j) acc ^= T[swz(cap_idx[j] + cO)];
            }

            out[r] = bs ^ acc;
        }
    } else {
        __syncthreads();   // match the single pre-ELEM barrier
        // generic tail (unused for bench shape: total % 2048 == 0)
        for (int e = 0; e < EPT; ++e) {
            const int r = r0 + e;
            if (r >= total) break;
            const int s = indptr[r], en = indptr[r + 1], len = en - s;
            bool lg, cp;
            if (layout4) {
                lg = ((const int*)legal_p)[r] != 0;
                cp = ((const int*)cap_p)[r]   != 0;
            } else {
                lg = ((const uint8_t*)legal_p)[r] != 0;
                cp = ((const uint8_t*)cap_p)[r]   != 0;
            }
            const unsigned bb = (unsigned)r / 361u;
            const int ii = r - (int)bb * 361;
            const int pp = cur_player[bb];
            const int cO = pp ? 0 : N2;
            int acc = 0;
            if (lg && cp) for (int j = s; j < en; ++j) acc ^= T[swz(cap_idx[j] + cO)];
            out[r] = cur_hash[bb] ^ T[swz(ii + (pp ? N2 : 0))] ^ acc;
        }
    }
}

extern "C" void kernel_launch(void* const* d_in, const int* in_sizes, int n_in,
                              void* d_out, int out_size, void* d_ws, size_t ws_size,
                              hipStream_t stream) {
    // 0: legal_mask (B,N2)  1: current_player (B,)  2: current_hash (B,)
    // 3: ZposT (3,N2)       4: can_capture_any (B,N2)
    // 5: cap_indptr (B*N2+1,)  6: cap_indices (L,)
    const void* legal  = d_in[0];
    const int*  player = (const int*)d_in[1];
    const int*  hash   = (const int*)d_in[2];
    const int*  Z      = (const int*)d_in[3];
    const void* cap    = d_in[4];
    const int*  indptr = (const int*)d_in[5];
    const int*  capidx = (const int*)d_in[6];
    int*        out    = (int*)d_out;

    const int total = out_size;            // B*N2 = 2,957,312
    const int Lm1   = in_sizes[6] - 1;
    const int Bm1   = in_sizes[1] - 1;

    const int blocks = (total + TPB * EPT - 1) / (TPB * EPT);   // 1444

    superko_fused<<<blocks, TPB, 0, stream>>>(legal, player, hash, Z, cap,
                                              indptr, capidx, out,
                                              total, Lm1, Bm1);
}